// Round 9
// baseline (173.988 us; speedup 1.0000x reference)
//
#include <hip/hip_runtime.h>
#include <hip/hip_bf16.h>

#define BB 16
#define NN 1024
#define CC 256

typedef __attribute__((ext_vector_type(8))) short bf16x8;
typedef __attribute__((ext_vector_type(4))) float f32x4;

#define GPTR(p) ((const __attribute__((address_space(1))) void*)(p))
#define LPTR(p) ((__attribute__((address_space(3))) void*)(p))

__device__ __forceinline__ unsigned short f2bf(float f) {
  union { float f; unsigned u; } v; v.f = f;
  unsigned r = v.u + 0x7FFFu + ((v.u >> 16) & 1u);
  return (unsigned short)(r >> 16);
}

// cast x -> xb, Wq|Wk|Wv -> wqkvb (768x256 bf16), bq|bk|bv -> bqkv (f32).
__global__ void cast_all(const float* __restrict__ x,
                         const float* __restrict__ Wq, const float* __restrict__ Wk,
                         const float* __restrict__ Wv,
                         const float* __restrict__ bq, const float* __restrict__ bk,
                         const float* __restrict__ bv,
                         unsigned short* __restrict__ xb,
                         unsigned short* __restrict__ wqkvb,
                         float* __restrict__ bqkv) {
  const int NX = BB * NN * CC;
  const int NW = CC * CC;
  int i = blockIdx.x * blockDim.x + threadIdx.x;
  if (i < NX) { xb[i] = f2bf(x[i]); return; }
  int j = i - NX;
  if (j < 3 * NW) {
    const float* w = (j < NW) ? Wq : (j < 2 * NW ? Wk : Wv);
    wqkvb[j] = f2bf(w[j % NW]);
    return;
  }
  int jj = j - 3 * NW;
  if (jj < 3 * CC) {
    const float* bb = (jj < CC) ? bq : (jj < 2 * CC ? bk : bv);
    bqkv[jj] = bb[jj % CC];
  }
}

// Amat[(h*32+w)][n] = Wp[h][n][w]   (Wp: (32, 1024, 32) f32)
__global__ __launch_bounds__(256) void wp_transpose(const float* __restrict__ Wp,
                                                    unsigned short* __restrict__ Amat) {
  __shared__ float tile[32][33];
  int h = blockIdx.y;
  int n0 = blockIdx.x * 32;
#pragma unroll
  for (int j = 0; j < 4; j++) {
    int idx = threadIdx.x + j * 256;
    int a = idx >> 5, wc = idx & 31;
    tile[a][wc] = Wp[(size_t)h * (NN * 32) + (size_t)(n0 + a) * 32 + wc];
  }
  __syncthreads();
#pragma unroll
  for (int j = 0; j < 4; j++) {
    int idx = threadIdx.x + j * 256;
    int wc = idx >> 5, a = idx & 31;
    Amat[(size_t)(h * 32 + wc) * NN + n0 + a] = f2bf(tile[a][wc]);
  }
}

// Tiled GEMM: C[m][n] = sum_k A[m][k]*Bt[n][k]. BM=128 BN=64 BK=64.
// Grid: (batch, m-tiles, n-tiles)  [batch on x => XCD affinity]
template <int BIAS_MODE, int F32OUT>
__global__ __launch_bounds__(256) void gemm_tile(
    const unsigned short* __restrict__ A, int lda, long sA,
    const unsigned short* __restrict__ Bt, int ldb, long sB,
    const float* __restrict__ bias,
    void* __restrict__ Out, int ldo, long sO, int K) {
  __shared__ unsigned short As[2 * 128 * 32];
  __shared__ unsigned short Bs[2 * 64 * 32];
  int b = blockIdx.x;
  int m0 = blockIdx.y * 128;
  int n0 = blockIdx.z * 64;
  int t = threadIdx.x;
  int w = t >> 6, lane = t & 63;
  int wm = (w >> 1) * 64, wn = (w & 1) * 32;
  int r = lane & 15, g = lane >> 4;

  const unsigned short* Ab = A + (long)b * sA;
  const unsigned short* Bb = Bt + (long)b * sB;

  int srow = t >> 2;
  int scol = (t & 3) * 8;

  f32x4 acc[4][2];
#pragma unroll
  for (int i = 0; i < 4; i++)
#pragma unroll
    for (int j = 0; j < 2; j++) acc[i][j] = (f32x4){0.f, 0.f, 0.f, 0.f};

  for (int k0 = 0; k0 < K; k0 += 64) {
    __syncthreads();
#pragma unroll
    for (int kh = 0; kh < 2; kh++) {
#pragma unroll
      for (int jj = 0; jj < 2; jj++) {
        __builtin_amdgcn_global_load_lds(
            GPTR(Ab + (long)(m0 + srow + jj * 64) * lda + k0 + kh * 32 + scol),
            LPTR(&As[kh * 4096 + jj * 2048 + t * 8]), 16, 0, 0);
      }
      __builtin_amdgcn_global_load_lds(
          GPTR(Bb + (long)(n0 + srow) * ldb + k0 + kh * 32 + scol),
          LPTR(&Bs[kh * 2048 + t * 8]), 16, 0, 0);
    }
    __syncthreads();
#pragma unroll
    for (int kh = 0; kh < 2; kh++) {
      bf16x8 af[4], bfr[2];
#pragma unroll
      for (int ti = 0; ti < 4; ti++)
        af[ti] = *(const bf16x8*)&As[kh * 4096 + (wm + ti * 16 + r) * 32 + g * 8];
#pragma unroll
      for (int tj = 0; tj < 2; tj++)
        bfr[tj] = *(const bf16x8*)&Bs[kh * 2048 + (wn + tj * 16 + r) * 32 + g * 8];
#pragma unroll
      for (int ti = 0; ti < 4; ti++)
#pragma unroll
        for (int tj = 0; tj < 2; tj++)
          acc[ti][tj] = __builtin_amdgcn_mfma_f32_16x16x32_bf16(af[ti], bfr[tj], acc[ti][tj], 0, 0, 0);
    }
  }

#pragma unroll
  for (int ti = 0; ti < 4; ti++) {
#pragma unroll
    for (int tj = 0; tj < 2; tj++) {
      int col = n0 + wn + tj * 16 + r;
      float bc = (BIAS_MODE == 1) ? bias[col] : 0.0f;
#pragma unroll
      for (int rr = 0; rr < 4; rr++) {
        int row = m0 + wm + ti * 16 + g * 4 + rr;
        float val = acc[ti][tj][rr] + bc;
        long oidx = (long)b * sO + (long)row * ldo + col;
        if (F32OUT)
          ((float*)Out)[oidx] = val;
        else
          ((unsigned short*)Out)[oidx] = f2bf(val);
      }
    }
  }
}

// Fused QKV projection. Grid: (batch, 8 m-tiles, 12 n-tiles).
// K written TILED: Kt[c>>5][tok][c&31]  (B-frag wave-loads contiguous 1 KB).
// V written TILED: V5[c>>4][m>>3][c&15][m&7] (phase-3 coalesced).
__global__ __launch_bounds__(256) void gemm_qkv(
    const unsigned short* __restrict__ A,
    const unsigned short* __restrict__ Bt,
    const float* __restrict__ bias,
    unsigned short* __restrict__ Qb, unsigned short* __restrict__ Kb,
    unsigned short* __restrict__ Vtb) {
  __shared__ unsigned short As[2 * 128 * 32];
  __shared__ unsigned short Bs[2 * 64 * 32];
  int b = blockIdx.x;
  int m0 = blockIdx.y * 128;
  int n0 = blockIdx.z * 64;
  int t = threadIdx.x;
  int w = t >> 6, lane = t & 63;
  int wm = (w >> 1) * 64, wn = (w & 1) * 32;
  int r = lane & 15, g = lane >> 4;

  const unsigned short* Ab = A + (long)b * NN * CC;
  int srow = t >> 2;
  int scol = (t & 3) * 8;

  f32x4 acc[4][2];
#pragma unroll
  for (int i = 0; i < 4; i++)
#pragma unroll
    for (int j = 0; j < 2; j++) acc[i][j] = (f32x4){0.f, 0.f, 0.f, 0.f};

  for (int k0 = 0; k0 < CC; k0 += 64) {
    __syncthreads();
#pragma unroll
    for (int kh = 0; kh < 2; kh++) {
#pragma unroll
      for (int jj = 0; jj < 2; jj++) {
        __builtin_amdgcn_global_load_lds(
            GPTR(Ab + (long)(m0 + srow + jj * 64) * CC + k0 + kh * 32 + scol),
            LPTR(&As[kh * 4096 + jj * 2048 + t * 8]), 16, 0, 0);
      }
      __builtin_amdgcn_global_load_lds(
          GPTR(Bt + (long)(n0 + srow) * CC + k0 + kh * 32 + scol),
          LPTR(&Bs[kh * 2048 + t * 8]), 16, 0, 0);
    }
    __syncthreads();
#pragma unroll
    for (int kh = 0; kh < 2; kh++) {
      bf16x8 af[4], bfr[2];
#pragma unroll
      for (int ti = 0; ti < 4; ti++)
        af[ti] = *(const bf16x8*)&As[kh * 4096 + (wm + ti * 16 + r) * 32 + g * 8];
#pragma unroll
      for (int tj = 0; tj < 2; tj++)
        bfr[tj] = *(const bf16x8*)&Bs[kh * 2048 + (wn + tj * 16 + r) * 32 + g * 8];
#pragma unroll
      for (int ti = 0; ti < 4; ti++)
#pragma unroll
        for (int tj = 0; tj < 2; tj++)
          acc[ti][tj] = __builtin_amdgcn_mfma_f32_16x16x32_bf16(af[ti], bfr[tj], acc[ti][tj], 0, 0, 0);
    }
  }

  int seg = n0 >> 8;
#pragma unroll
  for (int ti = 0; ti < 4; ti++) {
#pragma unroll
    for (int tj = 0; tj < 2; tj++) {
      int col = n0 + wn + tj * 16 + r;
      int c = col & 255;
      float bc = bias[col];
#pragma unroll
      for (int rr = 0; rr < 4; rr++) {
        int row = m0 + wm + ti * 16 + g * 4 + rr;   // token index
        float val = acc[ti][tj][rr] + bc;
        long base = (long)b * NN * CC;
        if (seg == 0) {
          Qb[base + (long)row * CC + c] = f2bf(val);
        } else if (seg == 1) {
          Kb[base + ((long)(c >> 5) * NN + row) * 32 + (c & 31)] = f2bf(val);
        } else {
          Vtb[base + ((((long)(c >> 4) * 128 + (row >> 3)) * 16 + (c & 15)) * 8 + (row & 7))] = f2bf(val);
        }
      }
    }
  }
}

// Fused scores+softmax+PV v5. 512 thr = 2 rg x 4 ch waves; 32 Q-rows/block.
// Grid (batch, 32): batch-major => XCD L2 affinity.
// Phase 1: QK^T with B-frags loaded DIRECT from tiled Kt (coalesced 1KB/wave,
//          zero barriers, 16 independent MFMA chains).
// Phase 2: P bf16 -> LDS, chunk-XOR swizzle (prow&7 — r6-measured variant).
// Phase 3: O = P V; A-frags from LDS; B-frags coalesced from tiled V5.
__global__ __launch_bounds__(512, 4) void attn_fused(
    const unsigned short* __restrict__ Q,    // [B][1024][256]
    const unsigned short* __restrict__ Kt,   // [B][8][1024][32] tiled
    const unsigned short* __restrict__ Vt,   // [B] tiled V5
    unsigned short* __restrict__ QKVt) {     // [B][256][1024]
  __shared__ unsigned short Ps[32 * 1024];   // 64 KB (P only)
  __shared__ float red[4][2][16];
  int b = blockIdx.x;
  int n0 = blockIdx.y * 32;
  int t = threadIdx.x;
  int w = t >> 6, lane = t & 63;
  int rg = w >> 2, ch = w & 3;
  int r = lane & 15, g = lane >> 4;

  const unsigned short* qbase = Q + ((long)b * NN + n0 + rg * 16 + r) * CC + g * 8;
  bf16x8 qf[8];
#pragma unroll
  for (int kk = 0; kk < 8; kk++) qf[kk] = *(const bf16x8*)(qbase + kk * 32);

  f32x4 acc[16];
#pragma unroll
  for (int tt = 0; tt < 16; tt++) acc[tt] = (f32x4){0.f, 0.f, 0.f, 0.f};

  // ---- phase 1: barrier-free QK^T ----
  const unsigned short* ktb = Kt + (long)b * NN * CC + ((long)ch * 256 + r) * 32 + g * 8;
  for (int kk = 0; kk < 8; kk++) {
    const unsigned short* kp = ktb + (long)kk * NN * 32;
#pragma unroll
    for (int tq = 0; tq < 4; tq++) {
      bf16x8 kv[4];
#pragma unroll
      for (int i = 0; i < 4; i++)
        kv[i] = *(const bf16x8*)(kp + (long)(tq * 4 + i) * 16 * 32);
#pragma unroll
      for (int i = 0; i < 4; i++)
        acc[tq * 4 + i] = __builtin_amdgcn_mfma_f32_16x16x32_bf16(qf[kk], kv[i], acc[tq * 4 + i], 0, 0, 0);
    }
  }

  // ---- softmax ----
  float mrow[4];
#pragma unroll
  for (int rr = 0; rr < 4; rr++) {
    float m = acc[0][rr];
#pragma unroll
    for (int tt = 1; tt < 16; tt++) m = fmaxf(m, acc[tt][rr]);
#pragma unroll
    for (int d = 1; d < 16; d <<= 1) m = fmaxf(m, __shfl_xor(m, d, 64));
    mrow[rr] = m;
  }
  if (r == 0) {
#pragma unroll
    for (int rr = 0; rr < 4; rr++) red[ch][rg][g * 4 + rr] = mrow[rr];
  }
  __syncthreads();
#pragma unroll
  for (int rr = 0; rr < 4; rr++) {
    float m = red[0][rg][g * 4 + rr];
#pragma unroll
    for (int c2 = 1; c2 < 4; c2++) m = fmaxf(m, red[c2][rg][g * 4 + rr]);
    mrow[rr] = m;
  }
  __syncthreads();  // WAR before sum overwrites red
  float ssum[4];
#pragma unroll
  for (int rr = 0; rr < 4; rr++) {
    float s = 0.f;
#pragma unroll
    for (int tt = 0; tt < 16; tt++) {
      float e = exp2f((acc[tt][rr] - mrow[rr]) * 1.44269504088896f);
      acc[tt][rr] = e;
      s += e;
    }
#pragma unroll
    for (int d = 1; d < 16; d <<= 1) s += __shfl_xor(s, d, 64);
    ssum[rr] = s;
  }
  if (r == 0) {
#pragma unroll
    for (int rr = 0; rr < 4; rr++) red[ch][rg][g * 4 + rr] = ssum[rr];
  }
  __syncthreads();
  // ---- phase 2: P -> LDS, chunk-XOR swizzle (prow&7) ----
#pragma unroll
  for (int rr = 0; rr < 4; rr++) {
    float s = red[0][rg][g * 4 + rr] + red[1][rg][g * 4 + rr] +
              red[2][rg][g * 4 + rr] + red[3][rg][g * 4 + rr];
    float inv = 1.0f / s;
    int prow = rg * 16 + g * 4 + rr;
    int sw = prow & 7;
#pragma unroll
    for (int tt = 0; tt < 16; tt++) {
      int col = ch * 256 + tt * 16 + r;
      int chunk = (col >> 3) ^ sw;
      Ps[prow * 1024 + chunk * 8 + (col & 7)] = f2bf(acc[tt][rr] * inv);
    }
  }
  __syncthreads();

  // ---- phase 3: O = P V.  Wave w owns O cols [w*32,+32), rows n0..n0+32.
  const unsigned short* vbase = Vt + (long)b * NN * CC;  // tiled V5
  int cw = w * 32;
  f32x4 o[2][2];
#pragma unroll
  for (int i = 0; i < 2; i++)
#pragma unroll
    for (int j = 0; j < 2; j++) o[i][j] = (f32x4){0.f, 0.f, 0.f, 0.f};

#pragma unroll 2
  for (int m0 = 0; m0 < NN; m0 += 32) {
    bf16x8 ar[2], br[2];
#pragma unroll
    for (int bt = 0; bt < 2; bt++) {
      long vidx = (((long)((cw >> 4) + bt) * 128 + (m0 >> 3) + g) * 16 + r) * 8;
      br[bt] = *(const bf16x8*)(vbase + vidx);
    }
#pragma unroll
    for (int rt = 0; rt < 2; rt++) {
      int prow = rt * 16 + r;
      int chunk = ((m0 >> 3) + g) ^ (prow & 7);
      ar[rt] = *(const bf16x8*)&Ps[prow * 1024 + chunk * 8];
    }
#pragma unroll
    for (int rt = 0; rt < 2; rt++)
#pragma unroll
      for (int bt = 0; bt < 2; bt++)
        o[rt][bt] = __builtin_amdgcn_mfma_f32_16x16x32_bf16(ar[rt], br[bt], o[rt][bt], 0, 0, 0);
  }

  unsigned short* obase = QKVt + (long)b * NN * CC;
#pragma unroll
  for (int rt = 0; rt < 2; rt++) {
#pragma unroll
    for (int bt = 0; bt < 2; bt++) {
      int c = cw + bt * 16 + r;
#pragma unroll
      for (int rr = 0; rr < 4; rr++) {
        int n = n0 + rt * 16 + g * 4 + rr;
        obase[(long)c * NN + n] = f2bf(o[rt][bt][rr]);
      }
    }
  }
}

extern "C" void kernel_launch(void* const* d_in, const int* in_sizes, int n_in,
                              void* d_out, int out_size, void* d_ws, size_t ws_size,
                              hipStream_t stream) {
  const float* x  = (const float*)d_in[0];
  const float* Wq = (const float*)d_in[1];
  const float* bq = (const float*)d_in[2];
  const float* Wk = (const float*)d_in[3];
  const float* bk = (const float*)d_in[4];
  const float* Wv = (const float*)d_in[5];
  const float* bv = (const float*)d_in[6];
  const float* Wp = (const float*)d_in[7];
  float* out = (float*)d_out;

  const long BNC = (long)BB * NN * CC;

  char* p = (char*)d_ws;
  unsigned short* xb    = (unsigned short*)p; p += BNC * 2;
  unsigned short* wqkvb = (unsigned short*)p; p += 3L * CC * CC * 2;
  float*          bqkv  = (float*)p;          p += 4096;
  unsigned short* Amat  = (unsigned short*)p; p += (long)NN * NN * 2;
  unsigned short* Qb    = (unsigned short*)p; p += BNC * 2;
  unsigned short* Ktb   = (unsigned short*)p; p += BNC * 2;   // tiled Kt
  unsigned short* Vtb   = (unsigned short*)p; p += BNC * 2;   // tiled V5
  unsigned short* QKVt  = (unsigned short*)p; p += BNC * 2;   // [b][c][n]

  const long TOT = BNC + 3L * CC * CC + 3 * CC;
  cast_all<<<(int)((TOT + 255) / 256), 256, 0, stream>>>(
      x, Wq, Wk, Wv, bq, bk, bv, xb, wqkvb, bqkv);
  wp_transpose<<<dim3(NN / 32, 32), 256, 0, stream>>>(Wp, Amat);

  // Fused QKV projection: M=1024, N=768, K=256 per batch (batch-major grid)
  gemm_qkv<<<dim3(BB, 8, 12), 256, 0, stream>>>(xb, wqkvb, bqkv, Qb, Ktb, Vtb);

  // Fused softmax(QK^T)·V -> QKVt[c][n]
  attn_fused<<<dim3(BB, NN / 32), 512, 0, stream>>>(Qb, Ktb, Vtb, QKVt);

  // Z[hw][c] = sum_n Amat[hw][n] * QKVt[c][n] : M=1024, N=256, K=1024, f32 out
  gemm_tile<0, 1><<<dim3(BB, 8, 4), 256, 0, stream>>>(
      Amat, NN, 0L, QKVt, NN, (long)NN * CC, nullptr,
      out, CC, (long)NN * CC, NN);
}

// Round 10
// 158.126 us; speedup vs baseline: 1.1003x; 1.1003x over previous
//
#include <hip/hip_runtime.h>
#include <hip/hip_bf16.h>

#define BB 16
#define NN 1024
#define CC 256

typedef __attribute__((ext_vector_type(8))) short bf16x8;
typedef __attribute__((ext_vector_type(4))) float f32x4;

#define GPTR(p) ((const __attribute__((address_space(1))) void*)(p))
#define LPTR(p) ((__attribute__((address_space(3))) void*)(p))

__device__ __forceinline__ unsigned short f2bf(float f) {
  union { float f; unsigned u; } v; v.f = f;
  unsigned r = v.u + 0x7FFFu + ((v.u >> 16) & 1u);
  return (unsigned short)(r >> 16);
}

// cast x -> xb, Wq|Wk|Wv -> wqkvb (768x256 bf16), bq|bk|bv -> bqkv (f32).
__global__ void cast_all(const float* __restrict__ x,
                         const float* __restrict__ Wq, const float* __restrict__ Wk,
                         const float* __restrict__ Wv,
                         const float* __restrict__ bq, const float* __restrict__ bk,
                         const float* __restrict__ bv,
                         unsigned short* __restrict__ xb,
                         unsigned short* __restrict__ wqkvb,
                         float* __restrict__ bqkv) {
  const int NX = BB * NN * CC;
  const int NW = CC * CC;
  int i = blockIdx.x * blockDim.x + threadIdx.x;
  if (i < NX) { xb[i] = f2bf(x[i]); return; }
  int j = i - NX;
  if (j < 3 * NW) {
    const float* w = (j < NW) ? Wq : (j < 2 * NW ? Wk : Wv);
    wqkvb[j] = f2bf(w[j % NW]);
    return;
  }
  int jj = j - 3 * NW;
  if (jj < 3 * CC) {
    const float* bb = (jj < CC) ? bq : (jj < 2 * CC ? bk : bv);
    bqkv[jj] = bb[jj % CC];
  }
}

// Amat[(h*32+w)][n] = Wp[h][n][w]   (Wp: (32, 1024, 32) f32)
__global__ __launch_bounds__(256) void wp_transpose(const float* __restrict__ Wp,
                                                    unsigned short* __restrict__ Amat) {
  __shared__ float tile[32][33];
  int h = blockIdx.y;
  int n0 = blockIdx.x * 32;
#pragma unroll
  for (int j = 0; j < 4; j++) {
    int idx = threadIdx.x + j * 256;
    int a = idx >> 5, wc = idx & 31;
    tile[a][wc] = Wp[(size_t)h * (NN * 32) + (size_t)(n0 + a) * 32 + wc];
  }
  __syncthreads();
#pragma unroll
  for (int j = 0; j < 4; j++) {
    int idx = threadIdx.x + j * 256;
    int wc = idx >> 5, a = idx & 31;
    Amat[(size_t)(h * 32 + wc) * NN + n0 + a] = f2bf(tile[a][wc]);
  }
}

// Tiled GEMM: C[m][n] = sum_k A[m][k]*Bt[n][k]. BM=128 BN=64 BK=64.
// Grid: (batch, m-tiles, n-tiles)  [batch on x => XCD affinity]
template <int BIAS_MODE, int F32OUT>
__global__ __launch_bounds__(256) void gemm_tile(
    const unsigned short* __restrict__ A, int lda, long sA,
    const unsigned short* __restrict__ Bt, int ldb, long sB,
    const float* __restrict__ bias,
    void* __restrict__ Out, int ldo, long sO, int K) {
  __shared__ unsigned short As[2 * 128 * 32];
  __shared__ unsigned short Bs[2 * 64 * 32];
  int b = blockIdx.x;
  int m0 = blockIdx.y * 128;
  int n0 = blockIdx.z * 64;
  int t = threadIdx.x;
  int w = t >> 6, lane = t & 63;
  int wm = (w >> 1) * 64, wn = (w & 1) * 32;
  int r = lane & 15, g = lane >> 4;

  const unsigned short* Ab = A + (long)b * sA;
  const unsigned short* Bb = Bt + (long)b * sB;

  int srow = t >> 2;
  int scol = (t & 3) * 8;

  f32x4 acc[4][2];
#pragma unroll
  for (int i = 0; i < 4; i++)
#pragma unroll
    for (int j = 0; j < 2; j++) acc[i][j] = (f32x4){0.f, 0.f, 0.f, 0.f};

  for (int k0 = 0; k0 < K; k0 += 64) {
    __syncthreads();
#pragma unroll
    for (int kh = 0; kh < 2; kh++) {
#pragma unroll
      for (int jj = 0; jj < 2; jj++) {
        __builtin_amdgcn_global_load_lds(
            GPTR(Ab + (long)(m0 + srow + jj * 64) * lda + k0 + kh * 32 + scol),
            LPTR(&As[kh * 4096 + jj * 2048 + t * 8]), 16, 0, 0);
      }
      __builtin_amdgcn_global_load_lds(
          GPTR(Bb + (long)(n0 + srow) * ldb + k0 + kh * 32 + scol),
          LPTR(&Bs[kh * 2048 + t * 8]), 16, 0, 0);
    }
    __syncthreads();
#pragma unroll
    for (int kh = 0; kh < 2; kh++) {
      bf16x8 af[4], bfr[2];
#pragma unroll
      for (int ti = 0; ti < 4; ti++)
        af[ti] = *(const bf16x8*)&As[kh * 4096 + (wm + ti * 16 + r) * 32 + g * 8];
#pragma unroll
      for (int tj = 0; tj < 2; tj++)
        bfr[tj] = *(const bf16x8*)&Bs[kh * 2048 + (wn + tj * 16 + r) * 32 + g * 8];
#pragma unroll
      for (int ti = 0; ti < 4; ti++)
#pragma unroll
        for (int tj = 0; tj < 2; tj++)
          acc[ti][tj] = __builtin_amdgcn_mfma_f32_16x16x32_bf16(af[ti], bfr[tj], acc[ti][tj], 0, 0, 0);
    }
  }

#pragma unroll
  for (int ti = 0; ti < 4; ti++) {
#pragma unroll
    for (int tj = 0; tj < 2; tj++) {
      int col = n0 + wn + tj * 16 + r;
      float bc = (BIAS_MODE == 1) ? bias[col] : 0.0f;
#pragma unroll
      for (int rr = 0; rr < 4; rr++) {
        int row = m0 + wm + ti * 16 + g * 4 + rr;
        float val = acc[ti][tj][rr] + bc;
        long oidx = (long)b * sO + (long)row * ldo + col;
        if (F32OUT)
          ((float*)Out)[oidx] = val;
        else
          ((unsigned short*)Out)[oidx] = f2bf(val);
      }
    }
  }
}

// Fused QKV projection. Grid: (batch, 8 m-tiles, 12 n-tiles).
// K written TILED: Kt[c>>5][tok][c&31]  (one kk-slab = contiguous 64 KB).
// V written TILED: V5[c>>4][m>>3][c&15][m&7] (phase-3 coalesced).
__global__ __launch_bounds__(256) void gemm_qkv(
    const unsigned short* __restrict__ A,
    const unsigned short* __restrict__ Bt,
    const float* __restrict__ bias,
    unsigned short* __restrict__ Qb, unsigned short* __restrict__ Kb,
    unsigned short* __restrict__ Vtb) {
  __shared__ unsigned short As[2 * 128 * 32];
  __shared__ unsigned short Bs[2 * 64 * 32];
  int b = blockIdx.x;
  int m0 = blockIdx.y * 128;
  int n0 = blockIdx.z * 64;
  int t = threadIdx.x;
  int w = t >> 6, lane = t & 63;
  int wm = (w >> 1) * 64, wn = (w & 1) * 32;
  int r = lane & 15, g = lane >> 4;

  const unsigned short* Ab = A + (long)b * NN * CC;
  int srow = t >> 2;
  int scol = (t & 3) * 8;

  f32x4 acc[4][2];
#pragma unroll
  for (int i = 0; i < 4; i++)
#pragma unroll
    for (int j = 0; j < 2; j++) acc[i][j] = (f32x4){0.f, 0.f, 0.f, 0.f};

  for (int k0 = 0; k0 < CC; k0 += 64) {
    __syncthreads();
#pragma unroll
    for (int kh = 0; kh < 2; kh++) {
#pragma unroll
      for (int jj = 0; jj < 2; jj++) {
        __builtin_amdgcn_global_load_lds(
            GPTR(Ab + (long)(m0 + srow + jj * 64) * CC + k0 + kh * 32 + scol),
            LPTR(&As[kh * 4096 + jj * 2048 + t * 8]), 16, 0, 0);
      }
      __builtin_amdgcn_global_load_lds(
          GPTR(Bt + (long)(n0 + srow) * CC + k0 + kh * 32 + scol),
          LPTR(&Bs[kh * 2048 + t * 8]), 16, 0, 0);
    }
    __syncthreads();
#pragma unroll
    for (int kh = 0; kh < 2; kh++) {
      bf16x8 af[4], bfr[2];
#pragma unroll
      for (int ti = 0; ti < 4; ti++)
        af[ti] = *(const bf16x8*)&As[kh * 4096 + (wm + ti * 16 + r) * 32 + g * 8];
#pragma unroll
      for (int tj = 0; tj < 2; tj++)
        bfr[tj] = *(const bf16x8*)&Bs[kh * 2048 + (wn + tj * 16 + r) * 32 + g * 8];
#pragma unroll
      for (int ti = 0; ti < 4; ti++)
#pragma unroll
        for (int tj = 0; tj < 2; tj++)
          acc[ti][tj] = __builtin_amdgcn_mfma_f32_16x16x32_bf16(af[ti], bfr[tj], acc[ti][tj], 0, 0, 0);
    }
  }

  int seg = n0 >> 8;
#pragma unroll
  for (int ti = 0; ti < 4; ti++) {
#pragma unroll
    for (int tj = 0; tj < 2; tj++) {
      int col = n0 + wn + tj * 16 + r;
      int c = col & 255;
      float bc = bias[col];
#pragma unroll
      for (int rr = 0; rr < 4; rr++) {
        int row = m0 + wm + ti * 16 + g * 4 + rr;   // token index
        float val = acc[ti][tj][rr] + bc;
        long base = (long)b * NN * CC;
        if (seg == 0) {
          Qb[base + (long)row * CC + c] = f2bf(val);
        } else if (seg == 1) {
          Kb[base + ((long)(c >> 5) * NN + row) * 32 + (c & 31)] = f2bf(val);
        } else {
          Vtb[base + ((((long)(c >> 4) * 128 + (row >> 3)) * 16 + (c & 15)) * 8 + (row & 7))] = f2bf(val);
        }
      }
    }
  }
}

// Fused scores+softmax+PV v6. 512 thr = 2 rg x 4 ch waves; 32 Q-rows/block.
// Grid (batch, 32): batch-major => XCD L2 affinity.
// Phase 1: K kk-slab (contiguous 64 KB in tiled Kt) staged via perfectly
//          linear global_load_lds (1 KB/wave-inst), then LDS-frag MFMA (r8
//          structure, r10 coalesced source).
// Phase 2: P bf16 -> LDS, chunk-XOR swizzle prow&7 (r9-measured best).
// Phase 3: O = P V; A-frags from LDS; B-frags coalesced direct from V5.
__global__ __launch_bounds__(512, 4) void attn_fused(
    const unsigned short* __restrict__ Q,    // [B][1024][256]
    const unsigned short* __restrict__ Kt,   // [B][8][1024][32] tiled
    const unsigned short* __restrict__ Vt,   // [B] tiled V5
    unsigned short* __restrict__ QKVt) {     // [B][256][1024]
  __shared__ unsigned short ShBuf[32 * 1024];  // 64 KB: K slab then P
  __shared__ float red[4][2][16];
  int b = blockIdx.x;
  int n0 = blockIdx.y * 32;
  int t = threadIdx.x;
  int w = t >> 6, lane = t & 63;
  int rg = w >> 2, ch = w & 3;
  int r = lane & 15, g = lane >> 4;

  const unsigned short* qbase = Q + ((long)b * NN + n0 + rg * 16 + r) * CC + g * 8;
  bf16x8 qf[8];
#pragma unroll
  for (int kk = 0; kk < 8; kk++) qf[kk] = *(const bf16x8*)(qbase + kk * 32);

  f32x4 acc[16];
#pragma unroll
  for (int tt = 0; tt < 16; tt++) acc[tt] = (f32x4){0.f, 0.f, 0.f, 0.f};

  // ---- phase 1: staged QK^T, linear 64 KB slab copies ----
  const unsigned short* kslab = Kt + (long)b * NN * CC;
  for (int kk = 0; kk < 8; kk++) {
    __syncthreads();
#pragma unroll
    for (int j = 0; j < 8; j++) {
      __builtin_amdgcn_global_load_lds(
          GPTR(kslab + (long)kk * NN * 32 + j * 4096 + t * 8),
          LPTR(&ShBuf[j * 4096 + t * 8]), 16, 0, 0);
    }
    __syncthreads();
#pragma unroll
    for (int tt = 0; tt < 16; tt++) {
      bf16x8 bv = *(const bf16x8*)&ShBuf[(ch * 256 + tt * 16 + r) * 32 + g * 8];
      acc[tt] = __builtin_amdgcn_mfma_f32_16x16x32_bf16(qf[kk], bv, acc[tt], 0, 0, 0);
    }
  }

  // ---- softmax ----
  float mrow[4];
#pragma unroll
  for (int rr = 0; rr < 4; rr++) {
    float m = acc[0][rr];
#pragma unroll
    for (int tt = 1; tt < 16; tt++) m = fmaxf(m, acc[tt][rr]);
#pragma unroll
    for (int d = 1; d < 16; d <<= 1) m = fmaxf(m, __shfl_xor(m, d, 64));
    mrow[rr] = m;
  }
  if (r == 0) {
#pragma unroll
    for (int rr = 0; rr < 4; rr++) red[ch][rg][g * 4 + rr] = mrow[rr];
  }
  __syncthreads();
#pragma unroll
  for (int rr = 0; rr < 4; rr++) {
    float m = red[0][rg][g * 4 + rr];
#pragma unroll
    for (int c2 = 1; c2 < 4; c2++) m = fmaxf(m, red[c2][rg][g * 4 + rr]);
    mrow[rr] = m;
  }
  __syncthreads();  // WAR before sum overwrites red
  float ssum[4];
#pragma unroll
  for (int rr = 0; rr < 4; rr++) {
    float s = 0.f;
#pragma unroll
    for (int tt = 0; tt < 16; tt++) {
      float e = exp2f((acc[tt][rr] - mrow[rr]) * 1.44269504088896f);
      acc[tt][rr] = e;
      s += e;
    }
#pragma unroll
    for (int d = 1; d < 16; d <<= 1) s += __shfl_xor(s, d, 64);
    ssum[rr] = s;
  }
  if (r == 0) {
#pragma unroll
    for (int rr = 0; rr < 4; rr++) red[ch][rg][g * 4 + rr] = ssum[rr];
  }
  __syncthreads();
  // ---- phase 2: P -> LDS, chunk-XOR swizzle (prow&7) ----
#pragma unroll
  for (int rr = 0; rr < 4; rr++) {
    float s = red[0][rg][g * 4 + rr] + red[1][rg][g * 4 + rr] +
              red[2][rg][g * 4 + rr] + red[3][rg][g * 4 + rr];
    float inv = 1.0f / s;
    int prow = rg * 16 + g * 4 + rr;
    int sw = prow & 7;
#pragma unroll
    for (int tt = 0; tt < 16; tt++) {
      int col = ch * 256 + tt * 16 + r;
      int chunk = (col >> 3) ^ sw;
      ShBuf[prow * 1024 + chunk * 8 + (col & 7)] = f2bf(acc[tt][rr] * inv);
    }
  }
  __syncthreads();

  // ---- phase 3: O = P V.  Wave w owns O cols [w*32,+32), rows n0..n0+32.
  const unsigned short* vbase = Vt + (long)b * NN * CC;  // tiled V5
  int cw = w * 32;
  f32x4 o[2][2];
#pragma unroll
  for (int i = 0; i < 2; i++)
#pragma unroll
    for (int j = 0; j < 2; j++) o[i][j] = (f32x4){0.f, 0.f, 0.f, 0.f};

#pragma unroll 2
  for (int m0 = 0; m0 < NN; m0 += 32) {
    bf16x8 ar[2], br[2];
#pragma unroll
    for (int bt = 0; bt < 2; bt++) {
      long vidx = (((long)((cw >> 4) + bt) * 128 + (m0 >> 3) + g) * 16 + r) * 8;
      br[bt] = *(const bf16x8*)(vbase + vidx);
    }
#pragma unroll
    for (int rt = 0; rt < 2; rt++) {
      int prow = rt * 16 + r;
      int chunk = ((m0 >> 3) + g) ^ (prow & 7);
      ar[rt] = *(const bf16x8*)&ShBuf[prow * 1024 + chunk * 8];
    }
#pragma unroll
    for (int rt = 0; rt < 2; rt++)
#pragma unroll
      for (int bt = 0; bt < 2; bt++)
        o[rt][bt] = __builtin_amdgcn_mfma_f32_16x16x32_bf16(ar[rt], br[bt], o[rt][bt], 0, 0, 0);
  }

  unsigned short* obase = QKVt + (long)b * NN * CC;
#pragma unroll
  for (int rt = 0; rt < 2; rt++) {
#pragma unroll
    for (int bt = 0; bt < 2; bt++) {
      int c = cw + bt * 16 + r;
#pragma unroll
      for (int rr = 0; rr < 4; rr++) {
        int n = n0 + rt * 16 + g * 4 + rr;
        obase[(long)c * NN + n] = f2bf(o[rt][bt][rr]);
      }
    }
  }
}

extern "C" void kernel_launch(void* const* d_in, const int* in_sizes, int n_in,
                              void* d_out, int out_size, void* d_ws, size_t ws_size,
                              hipStream_t stream) {
  const float* x  = (const float*)d_in[0];
  const float* Wq = (const float*)d_in[1];
  const float* bq = (const float*)d_in[2];
  const float* Wk = (const float*)d_in[3];
  const float* bk = (const float*)d_in[4];
  const float* Wv = (const float*)d_in[5];
  const float* bv = (const float*)d_in[6];
  const float* Wp = (const float*)d_in[7];
  float* out = (float*)d_out;

  const long BNC = (long)BB * NN * CC;

  char* p = (char*)d_ws;
  unsigned short* xb    = (unsigned short*)p; p += BNC * 2;
  unsigned short* wqkvb = (unsigned short*)p; p += 3L * CC * CC * 2;
  float*          bqkv  = (float*)p;          p += 4096;
  unsigned short* Amat  = (unsigned short*)p; p += (long)NN * NN * 2;
  unsigned short* Qb    = (unsigned short*)p; p += BNC * 2;
  unsigned short* Ktb   = (unsigned short*)p; p += BNC * 2;   // tiled Kt
  unsigned short* Vtb   = (unsigned short*)p; p += BNC * 2;   // tiled V5
  unsigned short* QKVt  = (unsigned short*)p; p += BNC * 2;   // [b][c][n]

  const long TOT = BNC + 3L * CC * CC + 3 * CC;
  cast_all<<<(int)((TOT + 255) / 256), 256, 0, stream>>>(
      x, Wq, Wk, Wv, bq, bk, bv, xb, wqkvb, bqkv);
  wp_transpose<<<dim3(NN / 32, 32), 256, 0, stream>>>(Wp, Amat);

  // Fused QKV projection: M=1024, N=768, K=256 per batch (batch-major grid)
  gemm_qkv<<<dim3(BB, 8, 12), 256, 0, stream>>>(xb, wqkvb, bqkv, Qb, Ktb, Vtb);

  // Fused softmax(QK^T)·V -> QKVt[c][n]
  attn_fused<<<dim3(BB, NN / 32), 512, 0, stream>>>(Qb, Ktb, Vtb, QKVt);

  // Z[hw][c] = sum_n Amat[hw][n] * QKVt[c][n] : M=1024, N=256, K=1024, f32 out
  gemm_tile<0, 1><<<dim3(BB, 8, 4), 256, 0, stream>>>(
      Amat, NN, 0L, QKVt, NN, (long)NN * CC, nullptr,
      out, CC, (long)NN * CC, NN);
}

// Round 11
// 153.662 us; speedup vs baseline: 1.1323x; 1.0290x over previous
//
#include <hip/hip_runtime.h>
#include <hip/hip_bf16.h>

#define BB 16
#define NN 1024
#define CC 256

typedef __attribute__((ext_vector_type(8))) short bf16x8;
typedef __attribute__((ext_vector_type(4))) float f32x4;

#define GPTR(p) ((const __attribute__((address_space(1))) void*)(p))
#define LPTR(p) ((__attribute__((address_space(3))) void*)(p))

__device__ __forceinline__ unsigned short f2bf(float f) {
  union { float f; unsigned u; } v; v.f = f;
  unsigned r = v.u + 0x7FFFu + ((v.u >> 16) & 1u);
  return (unsigned short)(r >> 16);
}

// Merged preprocessing: blocks [0, NCAST) cast x/W/b; blocks [NCAST, +1024)
// transpose Wp -> Amat.  NCAST = ceil((BNC + 3*NW + 3*CC)/256).
#define NCAST 17155
__global__ __launch_bounds__(256) void preprocess(
    const float* __restrict__ x,
    const float* __restrict__ Wq, const float* __restrict__ Wk,
    const float* __restrict__ Wv,
    const float* __restrict__ bq, const float* __restrict__ bk,
    const float* __restrict__ bv,
    const float* __restrict__ Wp,
    unsigned short* __restrict__ xb,
    unsigned short* __restrict__ wqkvb,
    float* __restrict__ bqkv,
    unsigned short* __restrict__ Amat) {
  __shared__ float tile[32][33];
  int blk = blockIdx.x;
  if (blk < NCAST) {
    const int NX = BB * NN * CC;
    const int NW = CC * CC;
    int i = blk * 256 + threadIdx.x;
    if (i < NX) { xb[i] = f2bf(x[i]); return; }
    int j = i - NX;
    if (j < 3 * NW) {
      const float* w = (j < NW) ? Wq : (j < 2 * NW ? Wk : Wv);
      wqkvb[j] = f2bf(w[j % NW]);
      return;
    }
    int jj = j - 3 * NW;
    if (jj < 3 * CC) {
      const float* bb = (jj < CC) ? bq : (jj < 2 * CC ? bk : bv);
      bqkv[jj] = bb[jj % CC];
    }
    return;
  }
  int wb = blk - NCAST;          // 0..1023
  int h = wb >> 5;
  int n0 = (wb & 31) * 32;
#pragma unroll
  for (int j = 0; j < 4; j++) {
    int idx = threadIdx.x + j * 256;
    int a = idx >> 5, wc = idx & 31;
    tile[a][wc] = Wp[(size_t)h * (NN * 32) + (size_t)(n0 + a) * 32 + wc];
  }
  __syncthreads();
#pragma unroll
  for (int j = 0; j < 4; j++) {
    int idx = threadIdx.x + j * 256;
    int wc = idx >> 5, a = idx & 31;
    Amat[(size_t)(h * 32 + wc) * NN + n0 + a] = f2bf(tile[a][wc]);
  }
}

// Tiled GEMM: C[m][n] = sum_k A[m][k]*Bt[n][k]. BM=128 BN=64 BK=64.
// Grid: (batch, m-tiles, n-tiles)  [batch on x => XCD affinity]
template <int BIAS_MODE, int F32OUT>
__global__ __launch_bounds__(256) void gemm_tile(
    const unsigned short* __restrict__ A, int lda, long sA,
    const unsigned short* __restrict__ Bt, int ldb, long sB,
    const float* __restrict__ bias,
    void* __restrict__ Out, int ldo, long sO, int K) {
  __shared__ unsigned short As[2 * 128 * 32];
  __shared__ unsigned short Bs[2 * 64 * 32];
  int b = blockIdx.x;
  int m0 = blockIdx.y * 128;
  int n0 = blockIdx.z * 64;
  int t = threadIdx.x;
  int w = t >> 6, lane = t & 63;
  int wm = (w >> 1) * 64, wn = (w & 1) * 32;
  int r = lane & 15, g = lane >> 4;

  const unsigned short* Ab = A + (long)b * sA;
  const unsigned short* Bb = Bt + (long)b * sB;

  int srow = t >> 2;
  int scol = (t & 3) * 8;

  f32x4 acc[4][2];
#pragma unroll
  for (int i = 0; i < 4; i++)
#pragma unroll
    for (int j = 0; j < 2; j++) acc[i][j] = (f32x4){0.f, 0.f, 0.f, 0.f};

  for (int k0 = 0; k0 < K; k0 += 64) {
    __syncthreads();
#pragma unroll
    for (int kh = 0; kh < 2; kh++) {
#pragma unroll
      for (int jj = 0; jj < 2; jj++) {
        __builtin_amdgcn_global_load_lds(
            GPTR(Ab + (long)(m0 + srow + jj * 64) * lda + k0 + kh * 32 + scol),
            LPTR(&As[kh * 4096 + jj * 2048 + t * 8]), 16, 0, 0);
      }
      __builtin_amdgcn_global_load_lds(
          GPTR(Bb + (long)(n0 + srow) * ldb + k0 + kh * 32 + scol),
          LPTR(&Bs[kh * 2048 + t * 8]), 16, 0, 0);
    }
    __syncthreads();
#pragma unroll
    for (int kh = 0; kh < 2; kh++) {
      bf16x8 af[4], bfr[2];
#pragma unroll
      for (int ti = 0; ti < 4; ti++)
        af[ti] = *(const bf16x8*)&As[kh * 4096 + (wm + ti * 16 + r) * 32 + g * 8];
#pragma unroll
      for (int tj = 0; tj < 2; tj++)
        bfr[tj] = *(const bf16x8*)&Bs[kh * 2048 + (wn + tj * 16 + r) * 32 + g * 8];
#pragma unroll
      for (int ti = 0; ti < 4; ti++)
#pragma unroll
        for (int tj = 0; tj < 2; tj++)
          acc[ti][tj] = __builtin_amdgcn_mfma_f32_16x16x32_bf16(af[ti], bfr[tj], acc[ti][tj], 0, 0, 0);
    }
  }

#pragma unroll
  for (int ti = 0; ti < 4; ti++) {
#pragma unroll
    for (int tj = 0; tj < 2; tj++) {
      int col = n0 + wn + tj * 16 + r;
      float bc = (BIAS_MODE == 1) ? bias[col] : 0.0f;
#pragma unroll
      for (int rr = 0; rr < 4; rr++) {
        int row = m0 + wm + ti * 16 + g * 4 + rr;
        float val = acc[ti][tj][rr] + bc;
        long oidx = (long)b * sO + (long)row * ldo + col;
        if (F32OUT)
          ((float*)Out)[oidx] = val;
        else
          ((unsigned short*)Out)[oidx] = f2bf(val);
      }
    }
  }
}

// Fused QKV projection, m97-style 128x128 tile, BK=32, acc 4x4.
// Grid: (batch, 8 m-tiles, 6 n-tiles of 128).  3 blocks/CU.
// K written TILED: Kt[c>>5][tok][c&31]; V TILED: V5[c>>4][m>>3][c&15][m&7].
__global__ __launch_bounds__(256) void gemm_qkv(
    const unsigned short* __restrict__ A,
    const unsigned short* __restrict__ Bt,
    const float* __restrict__ bias,
    unsigned short* __restrict__ Qb, unsigned short* __restrict__ Kb,
    unsigned short* __restrict__ Vtb) {
  __shared__ unsigned short As[128 * 32];
  __shared__ unsigned short Bs[128 * 32];
  int b = blockIdx.x;
  int m0 = blockIdx.y * 128;
  int n0 = blockIdx.z * 128;
  int t = threadIdx.x;
  int w = t >> 6, lane = t & 63;
  int wm = (w >> 1) * 64, wn = (w & 1) * 64;
  int r = lane & 15, g = lane >> 4;

  const unsigned short* Ab = A + (long)b * NN * CC;
  int srow = t >> 2;            // 0..63
  int scol = (t & 3) * 8;

  f32x4 acc[4][4];
#pragma unroll
  for (int i = 0; i < 4; i++)
#pragma unroll
    for (int j = 0; j < 4; j++) acc[i][j] = (f32x4){0.f, 0.f, 0.f, 0.f};

  for (int k0 = 0; k0 < CC; k0 += 32) {
    __syncthreads();
#pragma unroll
    for (int jj = 0; jj < 2; jj++) {
      __builtin_amdgcn_global_load_lds(
          GPTR(Ab + (long)(m0 + srow + jj * 64) * CC + k0 + scol),
          LPTR(&As[jj * 2048 + t * 8]), 16, 0, 0);
      __builtin_amdgcn_global_load_lds(
          GPTR(Bt + (long)(n0 + srow + jj * 64) * CC + k0 + scol),
          LPTR(&Bs[jj * 2048 + t * 8]), 16, 0, 0);
    }
    __syncthreads();
    bf16x8 af[4], bfr[4];
#pragma unroll
    for (int ti = 0; ti < 4; ti++)
      af[ti] = *(const bf16x8*)&As[(wm + ti * 16 + r) * 32 + g * 8];
#pragma unroll
    for (int tj = 0; tj < 4; tj++)
      bfr[tj] = *(const bf16x8*)&Bs[(wn + tj * 16 + r) * 32 + g * 8];
#pragma unroll
    for (int ti = 0; ti < 4; ti++)
#pragma unroll
      for (int tj = 0; tj < 4; tj++)
        acc[ti][tj] = __builtin_amdgcn_mfma_f32_16x16x32_bf16(af[ti], bfr[tj], acc[ti][tj], 0, 0, 0);
  }

  int seg = n0 >> 8;   // 128-col span stays within one 256-col segment
#pragma unroll
  for (int ti = 0; ti < 4; ti++) {
#pragma unroll
    for (int tj = 0; tj < 4; tj++) {
      int col = n0 + wn + tj * 16 + r;
      int c = col & 255;
      float bc = bias[col];
#pragma unroll
      for (int rr = 0; rr < 4; rr++) {
        int row = m0 + wm + ti * 16 + g * 4 + rr;   // token index
        float val = acc[ti][tj][rr] + bc;
        long base = (long)b * NN * CC;
        if (seg == 0) {
          Qb[base + (long)row * CC + c] = f2bf(val);
        } else if (seg == 1) {
          Kb[base + ((long)(c >> 5) * NN + row) * 32 + (c & 31)] = f2bf(val);
        } else {
          Vtb[base + ((((long)(c >> 4) * 128 + (row >> 3)) * 16 + (c & 15)) * 8 + (row & 7))] = f2bf(val);
        }
      }
    }
  }
}

// Fused scores+softmax+PV v7. 512 thr = 2 rg x 4 ch waves; 32 Q-rows/block.
// Grid (batch, 32): batch-major => XCD L2 affinity.
// Phase 1: linear 64 KB kk-slab staging from tiled Kt; Q preload overlaps
//          the first staging burst; 15 barriers (trailing one elided).
// Phase 2: P bf16 -> LDS, chunk-XOR swizzle prow&7.
// Phase 3: O = P V; A-frags from LDS; B-frags coalesced direct from V5.
__global__ __launch_bounds__(512, 4) void attn_fused(
    const unsigned short* __restrict__ Q,    // [B][1024][256]
    const unsigned short* __restrict__ Kt,   // [B][8][1024][32] tiled
    const unsigned short* __restrict__ Vt,   // [B] tiled V5
    unsigned short* __restrict__ QKVt) {     // [B][256][1024]
  __shared__ unsigned short ShBuf[32 * 1024];  // 64 KB: K slab then P
  __shared__ float red[4][2][16];
  int b = blockIdx.x;
  int n0 = blockIdx.y * 32;
  int t = threadIdx.x;
  int w = t >> 6, lane = t & 63;
  int rg = w >> 2, ch = w & 3;
  int r = lane & 15, g = lane >> 4;

  const unsigned short* kslab = Kt + (long)b * NN * CC;
  // issue kk=0 staging first; Q preload rides under it
#pragma unroll
  for (int j = 0; j < 8; j++) {
    __builtin_amdgcn_global_load_lds(
        GPTR(kslab + j * 4096 + t * 8),
        LPTR(&ShBuf[j * 4096 + t * 8]), 16, 0, 0);
  }
  const unsigned short* qbase = Q + ((long)b * NN + n0 + rg * 16 + r) * CC + g * 8;
  bf16x8 qf[8];
#pragma unroll
  for (int kk = 0; kk < 8; kk++) qf[kk] = *(const bf16x8*)(qbase + kk * 32);

  f32x4 acc[16];
#pragma unroll
  for (int tt = 0; tt < 16; tt++) acc[tt] = (f32x4){0.f, 0.f, 0.f, 0.f};

  for (int kk = 0; kk < 8; kk++) {
    __syncthreads();   // staging for kk visible
#pragma unroll
    for (int tt = 0; tt < 16; tt++) {
      bf16x8 bv = *(const bf16x8*)&ShBuf[(ch * 256 + tt * 16 + r) * 32 + g * 8];
      acc[tt] = __builtin_amdgcn_mfma_f32_16x16x32_bf16(qf[kk], bv, acc[tt], 0, 0, 0);
    }
    if (kk < 7) {
      __syncthreads();  // all reads of slab kk done
#pragma unroll
      for (int j = 0; j < 8; j++) {
        __builtin_amdgcn_global_load_lds(
            GPTR(kslab + (long)(kk + 1) * NN * 32 + j * 4096 + t * 8),
            LPTR(&ShBuf[j * 4096 + t * 8]), 16, 0, 0);
      }
    }
  }

  // ---- softmax ----
  float mrow[4];
#pragma unroll
  for (int rr = 0; rr < 4; rr++) {
    float m = acc[0][rr];
#pragma unroll
    for (int tt = 1; tt < 16; tt++) m = fmaxf(m, acc[tt][rr]);
#pragma unroll
    for (int d = 1; d < 16; d <<= 1) m = fmaxf(m, __shfl_xor(m, d, 64));
    mrow[rr] = m;
  }
  if (r == 0) {
#pragma unroll
    for (int rr = 0; rr < 4; rr++) red[ch][rg][g * 4 + rr] = mrow[rr];
  }
  __syncthreads();
#pragma unroll
  for (int rr = 0; rr < 4; rr++) {
    float m = red[0][rg][g * 4 + rr];
#pragma unroll
    for (int c2 = 1; c2 < 4; c2++) m = fmaxf(m, red[c2][rg][g * 4 + rr]);
    mrow[rr] = m;
  }
  __syncthreads();  // WAR before sum overwrites red
  float ssum[4];
#pragma unroll
  for (int rr = 0; rr < 4; rr++) {
    float s = 0.f;
#pragma unroll
    for (int tt = 0; tt < 16; tt++) {
      float e = exp2f((acc[tt][rr] - mrow[rr]) * 1.44269504088896f);
      acc[tt][rr] = e;
      s += e;
    }
#pragma unroll
    for (int d = 1; d < 16; d <<= 1) s += __shfl_xor(s, d, 64);
    ssum[rr] = s;
  }
  if (r == 0) {
#pragma unroll
    for (int rr = 0; rr < 4; rr++) red[ch][rg][g * 4 + rr] = ssum[rr];
  }
  __syncthreads();
  // ---- phase 2: P -> LDS, chunk-XOR swizzle (prow&7) ----
#pragma unroll
  for (int rr = 0; rr < 4; rr++) {
    float s = red[0][rg][g * 4 + rr] + red[1][rg][g * 4 + rr] +
              red[2][rg][g * 4 + rr] + red[3][rg][g * 4 + rr];
    float inv = 1.0f / s;
    int prow = rg * 16 + g * 4 + rr;
    int sw = prow & 7;
#pragma unroll
    for (int tt = 0; tt < 16; tt++) {
      int col = ch * 256 + tt * 16 + r;
      int chunk = (col >> 3) ^ sw;
      ShBuf[prow * 1024 + chunk * 8 + (col & 7)] = f2bf(acc[tt][rr] * inv);
    }
  }
  __syncthreads();

  // ---- phase 3: O = P V.  Wave w owns O cols [w*32,+32), rows n0..n0+32.
  const unsigned short* vbase = Vt + (long)b * NN * CC;  // tiled V5
  int cw = w * 32;
  f32x4 o[2][2];
#pragma unroll
  for (int i = 0; i < 2; i++)
#pragma unroll
    for (int j = 0; j < 2; j++) o[i][j] = (f32x4){0.f, 0.f, 0.f, 0.f};

#pragma unroll 2
  for (int m0 = 0; m0 < NN; m0 += 32) {
    bf16x8 ar[2], br[2];
#pragma unroll
    for (int bt = 0; bt < 2; bt++) {
      long vidx = (((long)((cw >> 4) + bt) * 128 + (m0 >> 3) + g) * 16 + r) * 8;
      br[bt] = *(const bf16x8*)(vbase + vidx);
    }
#pragma unroll
    for (int rt = 0; rt < 2; rt++) {
      int prow = rt * 16 + r;
      int chunk = ((m0 >> 3) + g) ^ (prow & 7);
      ar[rt] = *(const bf16x8*)&ShBuf[prow * 1024 + chunk * 8];
    }
#pragma unroll
    for (int rt = 0; rt < 2; rt++)
#pragma unroll
      for (int bt = 0; bt < 2; bt++)
        o[rt][bt] = __builtin_amdgcn_mfma_f32_16x16x32_bf16(ar[rt], br[bt], o[rt][bt], 0, 0, 0);
  }

  unsigned short* obase = QKVt + (long)b * NN * CC;
#pragma unroll
  for (int rt = 0; rt < 2; rt++) {
#pragma unroll
    for (int bt = 0; bt < 2; bt++) {
      int c = cw + bt * 16 + r;
#pragma unroll
      for (int rr = 0; rr < 4; rr++) {
        int n = n0 + rt * 16 + g * 4 + rr;
        obase[(long)c * NN + n] = f2bf(o[rt][bt][rr]);
      }
    }
  }
}

extern "C" void kernel_launch(void* const* d_in, const int* in_sizes, int n_in,
                              void* d_out, int out_size, void* d_ws, size_t ws_size,
                              hipStream_t stream) {
  const float* x  = (const float*)d_in[0];
  const float* Wq = (const float*)d_in[1];
  const float* bq = (const float*)d_in[2];
  const float* Wk = (const float*)d_in[3];
  const float* bk = (const float*)d_in[4];
  const float* Wv = (const float*)d_in[5];
  const float* bv = (const float*)d_in[6];
  const float* Wp = (const float*)d_in[7];
  float* out = (float*)d_out;

  const long BNC = (long)BB * NN * CC;

  char* p = (char*)d_ws;
  unsigned short* xb    = (unsigned short*)p; p += BNC * 2;
  unsigned short* wqkvb = (unsigned short*)p; p += 3L * CC * CC * 2;
  float*          bqkv  = (float*)p;          p += 4096;
  unsigned short* Amat  = (unsigned short*)p; p += (long)NN * NN * 2;
  unsigned short* Qb    = (unsigned short*)p; p += BNC * 2;
  unsigned short* Ktb   = (unsigned short*)p; p += BNC * 2;   // tiled Kt
  unsigned short* Vtb   = (unsigned short*)p; p += BNC * 2;   // tiled V5
  unsigned short* QKVt  = (unsigned short*)p; p += BNC * 2;   // [b][c][n]

  // casts + Wp transpose in one launch
  preprocess<<<NCAST + 1024, 256, 0, stream>>>(
      x, Wq, Wk, Wv, bq, bk, bv, Wp, xb, wqkvb, bqkv, Amat);

  // Fused QKV projection: M=1024, N=768, K=256 per batch; 128x128 tiles
  gemm_qkv<<<dim3(BB, 8, 6), 256, 0, stream>>>(xb, wqkvb, bqkv, Qb, Ktb, Vtb);

  // Fused softmax(QK^T)·V -> QKVt[c][n]
  attn_fused<<<dim3(BB, NN / 32), 512, 0, stream>>>(Qb, Ktb, Vtb, QKVt);

  // Z[hw][c] = sum_n Amat[hw][n] * QKVt[c][n] : M=1024, N=256, K=1024, f32 out
  gemm_tile<0, 1><<<dim3(BB, 8, 4), 256, 0, stream>>>(
      Amat, NN, 0L, QKVt, NN, (long)NN * CC, nullptr,
      out, CC, (long)NN * CC, NN);
}

// Round 12
// 151.658 us; speedup vs baseline: 1.1472x; 1.0132x over previous
//
#include <hip/hip_runtime.h>
#include <hip/hip_bf16.h>

#define BB 16
#define NN 1024
#define CC 256

typedef __attribute__((ext_vector_type(8))) short bf16x8;
typedef __attribute__((ext_vector_type(4))) float f32x4;

#define GPTR(p) ((const __attribute__((address_space(1))) void*)(p))
#define LPTR(p) ((__attribute__((address_space(3))) void*)(p))

__device__ __forceinline__ unsigned short f2bf(float f) {
  union { float f; unsigned u; } v; v.f = f;
  unsigned r = v.u + 0x7FFFu + ((v.u >> 16) & 1u);
  return (unsigned short)(r >> 16);
}

// Merged preprocessing: blocks [0, NCAST) cast x/W/b; blocks [NCAST, +1024)
// transpose Wp -> Amat.
#define NCAST 17155
__global__ __launch_bounds__(256) void preprocess(
    const float* __restrict__ x,
    const float* __restrict__ Wq, const float* __restrict__ Wk,
    const float* __restrict__ Wv,
    const float* __restrict__ bq, const float* __restrict__ bk,
    const float* __restrict__ bv,
    const float* __restrict__ Wp,
    unsigned short* __restrict__ xb,
    unsigned short* __restrict__ wqkvb,
    float* __restrict__ bqkv,
    unsigned short* __restrict__ Amat) {
  __shared__ float tile[32][33];
  int blk = blockIdx.x;
  if (blk < NCAST) {
    const int NX = BB * NN * CC;
    const int NW = CC * CC;
    int i = blk * 256 + threadIdx.x;
    if (i < NX) { xb[i] = f2bf(x[i]); return; }
    int j = i - NX;
    if (j < 3 * NW) {
      const float* w = (j < NW) ? Wq : (j < 2 * NW ? Wk : Wv);
      wqkvb[j] = f2bf(w[j % NW]);
      return;
    }
    int jj = j - 3 * NW;
    if (jj < 3 * CC) {
      const float* bb = (jj < CC) ? bq : (jj < 2 * CC ? bk : bv);
      bqkv[jj] = bb[jj % CC];
    }
    return;
  }
  int wb = blk - NCAST;          // 0..1023
  int h = wb >> 5;
  int n0 = (wb & 31) * 32;
#pragma unroll
  for (int j = 0; j < 4; j++) {
    int idx = threadIdx.x + j * 256;
    int a = idx >> 5, wc = idx & 31;
    tile[a][wc] = Wp[(size_t)h * (NN * 32) + (size_t)(n0 + a) * 32 + wc];
  }
  __syncthreads();
#pragma unroll
  for (int j = 0; j < 4; j++) {
    int idx = threadIdx.x + j * 256;
    int wc = idx >> 5, a = idx & 31;
    Amat[(size_t)(h * 32 + wc) * NN + n0 + a] = f2bf(tile[a][wc]);
  }
}

// Tiled GEMM: C[m][n] = sum_k A[m][k]*Bt[n][k]. BM=128 BN=64 BK=64.
// Grid: (batch, m-tiles, n-tiles)  [batch on x => XCD affinity]
template <int BIAS_MODE, int F32OUT>
__global__ __launch_bounds__(256) void gemm_tile(
    const unsigned short* __restrict__ A, int lda, long sA,
    const unsigned short* __restrict__ Bt, int ldb, long sB,
    const float* __restrict__ bias,
    void* __restrict__ Out, int ldo, long sO, int K) {
  __shared__ unsigned short As[2 * 128 * 32];
  __shared__ unsigned short Bs[2 * 64 * 32];
  int b = blockIdx.x;
  int m0 = blockIdx.y * 128;
  int n0 = blockIdx.z * 64;
  int t = threadIdx.x;
  int w = t >> 6, lane = t & 63;
  int wm = (w >> 1) * 64, wn = (w & 1) * 32;
  int r = lane & 15, g = lane >> 4;

  const unsigned short* Ab = A + (long)b * sA;
  const unsigned short* Bb = Bt + (long)b * sB;

  int srow = t >> 2;
  int scol = (t & 3) * 8;

  f32x4 acc[4][2];
#pragma unroll
  for (int i = 0; i < 4; i++)
#pragma unroll
    for (int j = 0; j < 2; j++) acc[i][j] = (f32x4){0.f, 0.f, 0.f, 0.f};

  for (int k0 = 0; k0 < K; k0 += 64) {
    __syncthreads();
#pragma unroll
    for (int kh = 0; kh < 2; kh++) {
#pragma unroll
      for (int jj = 0; jj < 2; jj++) {
        __builtin_amdgcn_global_load_lds(
            GPTR(Ab + (long)(m0 + srow + jj * 64) * lda + k0 + kh * 32 + scol),
            LPTR(&As[kh * 4096 + jj * 2048 + t * 8]), 16, 0, 0);
      }
      __builtin_amdgcn_global_load_lds(
          GPTR(Bb + (long)(n0 + srow) * ldb + k0 + kh * 32 + scol),
          LPTR(&Bs[kh * 2048 + t * 8]), 16, 0, 0);
    }
    __syncthreads();
#pragma unroll
    for (int kh = 0; kh < 2; kh++) {
      bf16x8 af[4], bfr[2];
#pragma unroll
      for (int ti = 0; ti < 4; ti++)
        af[ti] = *(const bf16x8*)&As[kh * 4096 + (wm + ti * 16 + r) * 32 + g * 8];
#pragma unroll
      for (int tj = 0; tj < 2; tj++)
        bfr[tj] = *(const bf16x8*)&Bs[kh * 2048 + (wn + tj * 16 + r) * 32 + g * 8];
#pragma unroll
      for (int ti = 0; ti < 4; ti++)
#pragma unroll
        for (int tj = 0; tj < 2; tj++)
          acc[ti][tj] = __builtin_amdgcn_mfma_f32_16x16x32_bf16(af[ti], bfr[tj], acc[ti][tj], 0, 0, 0);
    }
  }

#pragma unroll
  for (int ti = 0; ti < 4; ti++) {
#pragma unroll
    for (int tj = 0; tj < 2; tj++) {
      int col = n0 + wn + tj * 16 + r;
      float bc = (BIAS_MODE == 1) ? bias[col] : 0.0f;
#pragma unroll
      for (int rr = 0; rr < 4; rr++) {
        int row = m0 + wm + ti * 16 + g * 4 + rr;
        float val = acc[ti][tj][rr] + bc;
        long oidx = (long)b * sO + (long)row * ldo + col;
        if (F32OUT)
          ((float*)Out)[oidx] = val;
        else
          ((unsigned short*)Out)[oidx] = f2bf(val);
      }
    }
  }
}

// Fused QKV projection, 128x128 tile, BK=64 (two k-panels, 8 barriers).
// Grid: (batch, 8 m-tiles, 6 n-tiles of 128).  3 blocks/CU.
// K written TILED: Kt[c>>5][tok][c&31]; V TILED: V5[c>>4][m>>3][c&15][m&7].
__global__ __launch_bounds__(256) void gemm_qkv(
    const unsigned short* __restrict__ A,
    const unsigned short* __restrict__ Bt,
    const float* __restrict__ bias,
    unsigned short* __restrict__ Qb, unsigned short* __restrict__ Kb,
    unsigned short* __restrict__ Vtb) {
  __shared__ unsigned short As[2 * 128 * 32];  // 16 KB
  __shared__ unsigned short Bs[2 * 128 * 32];  // 16 KB
  int b = blockIdx.x;
  int m0 = blockIdx.y * 128;
  int n0 = blockIdx.z * 128;
  int t = threadIdx.x;
  int w = t >> 6, lane = t & 63;
  int wm = (w >> 1) * 64, wn = (w & 1) * 64;
  int r = lane & 15, g = lane >> 4;

  const unsigned short* Ab = A + (long)b * NN * CC;
  int srow = t >> 2;            // 0..63
  int scol = (t & 3) * 8;

  f32x4 acc[4][4];
#pragma unroll
  for (int i = 0; i < 4; i++)
#pragma unroll
    for (int j = 0; j < 4; j++) acc[i][j] = (f32x4){0.f, 0.f, 0.f, 0.f};

  for (int k0 = 0; k0 < CC; k0 += 64) {
    __syncthreads();
#pragma unroll
    for (int kh = 0; kh < 2; kh++) {
#pragma unroll
      for (int jj = 0; jj < 2; jj++) {
        __builtin_amdgcn_global_load_lds(
            GPTR(Ab + (long)(m0 + srow + jj * 64) * CC + k0 + kh * 32 + scol),
            LPTR(&As[kh * 4096 + jj * 2048 + t * 8]), 16, 0, 0);
        __builtin_amdgcn_global_load_lds(
            GPTR(Bt + (long)(n0 + srow + jj * 64) * CC + k0 + kh * 32 + scol),
            LPTR(&Bs[kh * 4096 + jj * 2048 + t * 8]), 16, 0, 0);
      }
    }
    __syncthreads();
#pragma unroll
    for (int kh = 0; kh < 2; kh++) {
      bf16x8 af[4], bfr[4];
#pragma unroll
      for (int ti = 0; ti < 4; ti++)
        af[ti] = *(const bf16x8*)&As[kh * 4096 + (wm + ti * 16 + r) * 32 + g * 8];
#pragma unroll
      for (int tj = 0; tj < 4; tj++)
        bfr[tj] = *(const bf16x8*)&Bs[kh * 4096 + (wn + tj * 16 + r) * 32 + g * 8];
#pragma unroll
      for (int ti = 0; ti < 4; ti++)
#pragma unroll
        for (int tj = 0; tj < 4; tj++)
          acc[ti][tj] = __builtin_amdgcn_mfma_f32_16x16x32_bf16(af[ti], bfr[tj], acc[ti][tj], 0, 0, 0);
    }
  }

  int seg = n0 >> 8;   // 128-col span stays within one 256-col segment
#pragma unroll
  for (int ti = 0; ti < 4; ti++) {
#pragma unroll
    for (int tj = 0; tj < 4; tj++) {
      int col = n0 + wn + tj * 16 + r;
      int c = col & 255;
      float bc = bias[col];
#pragma unroll
      for (int rr = 0; rr < 4; rr++) {
        int row = m0 + wm + ti * 16 + g * 4 + rr;   // token index
        float val = acc[ti][tj][rr] + bc;
        long base = (long)b * NN * CC;
        if (seg == 0) {
          Qb[base + (long)row * CC + c] = f2bf(val);
        } else if (seg == 1) {
          Kb[base + ((long)(c >> 5) * NN + row) * 32 + (c & 31)] = f2bf(val);
        } else {
          Vtb[base + ((((long)(c >> 4) * 128 + (row >> 3)) * 16 + (c & 15)) * 8 + (row & 7))] = f2bf(val);
        }
      }
    }
  }
}

// Fused scores+softmax+PV v8. 512 thr = 2 rg x 4 ch waves; 32 Q-rows/block.
// Grid (batch, 32): batch-major => XCD L2 affinity.
// Phase 1: linear 64 KB kk-slab staging from tiled Kt; Q loaded PER kk (one
//          bf16x8, next-iter load hidden under MFMAs) — frees ~28 VGPRs vs
//          qf[8] preload, raising the register-capped occupancy.
// Phase 2: P bf16 -> LDS, chunk-XOR swizzle prow&7.
// Phase 3: O = P V, unroll 4 (acc dead here; freed AGPRs hold the loads).
__global__ __launch_bounds__(512, 4) void attn_fused(
    const unsigned short* __restrict__ Q,    // [B][1024][256]
    const unsigned short* __restrict__ Kt,   // [B][8][1024][32] tiled
    const unsigned short* __restrict__ Vt,   // [B] tiled V5
    unsigned short* __restrict__ QKVt) {     // [B][256][1024]
  __shared__ unsigned short ShBuf[32 * 1024];  // 64 KB: K slab then P
  __shared__ float red[4][2][16];
  int b = blockIdx.x;
  int n0 = blockIdx.y * 32;
  int t = threadIdx.x;
  int w = t >> 6, lane = t & 63;
  int rg = w >> 2, ch = w & 3;
  int r = lane & 15, g = lane >> 4;

  const unsigned short* kslab = Kt + (long)b * NN * CC;
  // issue kk=0 staging first; Q load rides under it
#pragma unroll
  for (int j = 0; j < 8; j++) {
    __builtin_amdgcn_global_load_lds(
        GPTR(kslab + j * 4096 + t * 8),
        LPTR(&ShBuf[j * 4096 + t * 8]), 16, 0, 0);
  }
  const unsigned short* qbase = Q + ((long)b * NN + n0 + rg * 16 + r) * CC + g * 8;
  bf16x8 qv = *(const bf16x8*)qbase;

  f32x4 acc[16];
#pragma unroll
  for (int tt = 0; tt < 16; tt++) acc[tt] = (f32x4){0.f, 0.f, 0.f, 0.f};

  for (int kk = 0; kk < 8; kk++) {
    __syncthreads();   // staging for kk visible
    bf16x8 qnext;
    if (kk < 7) qnext = *(const bf16x8*)(qbase + (kk + 1) * 32);
#pragma unroll
    for (int tt = 0; tt < 16; tt++) {
      bf16x8 bv = *(const bf16x8*)&ShBuf[(ch * 256 + tt * 16 + r) * 32 + g * 8];
      acc[tt] = __builtin_amdgcn_mfma_f32_16x16x32_bf16(qv, bv, acc[tt], 0, 0, 0);
    }
    if (kk < 7) {
      __syncthreads();  // all reads of slab kk done
#pragma unroll
      for (int j = 0; j < 8; j++) {
        __builtin_amdgcn_global_load_lds(
            GPTR(kslab + (long)(kk + 1) * NN * 32 + j * 4096 + t * 8),
            LPTR(&ShBuf[j * 4096 + t * 8]), 16, 0, 0);
      }
      qv = qnext;
    }
  }

  // ---- softmax ----
  float mrow[4];
#pragma unroll
  for (int rr = 0; rr < 4; rr++) {
    float m = acc[0][rr];
#pragma unroll
    for (int tt = 1; tt < 16; tt++) m = fmaxf(m, acc[tt][rr]);
#pragma unroll
    for (int d = 1; d < 16; d <<= 1) m = fmaxf(m, __shfl_xor(m, d, 64));
    mrow[rr] = m;
  }
  if (r == 0) {
#pragma unroll
    for (int rr = 0; rr < 4; rr++) red[ch][rg][g * 4 + rr] = mrow[rr];
  }
  __syncthreads();
#pragma unroll
  for (int rr = 0; rr < 4; rr++) {
    float m = red[0][rg][g * 4 + rr];
#pragma unroll
    for (int c2 = 1; c2 < 4; c2++) m = fmaxf(m, red[c2][rg][g * 4 + rr]);
    mrow[rr] = m;
  }
  __syncthreads();  // WAR before sum overwrites red
  float ssum[4];
#pragma unroll
  for (int rr = 0; rr < 4; rr++) {
    float s = 0.f;
#pragma unroll
    for (int tt = 0; tt < 16; tt++) {
      float e = exp2f((acc[tt][rr] - mrow[rr]) * 1.44269504088896f);
      acc[tt][rr] = e;
      s += e;
    }
#pragma unroll
    for (int d = 1; d < 16; d <<= 1) s += __shfl_xor(s, d, 64);
    ssum[rr] = s;
  }
  if (r == 0) {
#pragma unroll
    for (int rr = 0; rr < 4; rr++) red[ch][rg][g * 4 + rr] = ssum[rr];
  }
  __syncthreads();
  // ---- phase 2: P -> LDS, chunk-XOR swizzle (prow&7) ----
#pragma unroll
  for (int rr = 0; rr < 4; rr++) {
    float s = red[0][rg][g * 4 + rr] + red[1][rg][g * 4 + rr] +
              red[2][rg][g * 4 + rr] + red[3][rg][g * 4 + rr];
    float inv = 1.0f / s;
    int prow = rg * 16 + g * 4 + rr;
    int sw = prow & 7;
#pragma unroll
    for (int tt = 0; tt < 16; tt++) {
      int col = ch * 256 + tt * 16 + r;
      int chunk = (col >> 3) ^ sw;
      ShBuf[prow * 1024 + chunk * 8 + (col & 7)] = f2bf(acc[tt][rr] * inv);
    }
  }
  __syncthreads();

  // ---- phase 3: O = P V.  Wave w owns O cols [w*32,+32), rows n0..n0+32.
  const unsigned short* vbase = Vt + (long)b * NN * CC;  // tiled V5
  int cw = w * 32;
  f32x4 o[2][2];
#pragma unroll
  for (int i = 0; i < 2; i++)
#pragma unroll
    for (int j = 0; j < 2; j++) o[i][j] = (f32x4){0.f, 0.f, 0.f, 0.f};

#pragma unroll 4
  for (int m0 = 0; m0 < NN; m0 += 32) {
    bf16x8 ar[2], br[2];
#pragma unroll
    for (int bt = 0; bt < 2; bt++) {
      long vidx = (((long)((cw >> 4) + bt) * 128 + (m0 >> 3) + g) * 16 + r) * 8;
      br[bt] = *(const bf16x8*)(vbase + vidx);
    }
#pragma unroll
    for (int rt = 0; rt < 2; rt++) {
      int prow = rt * 16 + r;
      int chunk = ((m0 >> 3) + g) ^ (prow & 7);
      ar[rt] = *(const bf16x8*)&ShBuf[prow * 1024 + chunk * 8];
    }
#pragma unroll
    for (int rt = 0; rt < 2; rt++)
#pragma unroll
      for (int bt = 0; bt < 2; bt++)
        o[rt][bt] = __builtin_amdgcn_mfma_f32_16x16x32_bf16(ar[rt], br[bt], o[rt][bt], 0, 0, 0);
  }

  unsigned short* obase = QKVt + (long)b * NN * CC;
#pragma unroll
  for (int rt = 0; rt < 2; rt++) {
#pragma unroll
    for (int bt = 0; bt < 2; bt++) {
      int c = cw + bt * 16 + r;
#pragma unroll
      for (int rr = 0; rr < 4; rr++) {
        int n = n0 + rt * 16 + g * 4 + rr;
        obase[(long)c * NN + n] = f2bf(o[rt][bt][rr]);
      }
    }
  }
}

extern "C" void kernel_launch(void* const* d_in, const int* in_sizes, int n_in,
                              void* d_out, int out_size, void* d_ws, size_t ws_size,
                              hipStream_t stream) {
  const float* x  = (const float*)d_in[0];
  const float* Wq = (const float*)d_in[1];
  const float* bq = (const float*)d_in[2];
  const float* Wk = (const float*)d_in[3];
  const float* bk = (const float*)d_in[4];
  const float* Wv = (const float*)d_in[5];
  const float* bv = (const float*)d_in[6];
  const float* Wp = (const float*)d_in[7];
  float* out = (float*)d_out;

  const long BNC = (long)BB * NN * CC;

  char* p = (char*)d_ws;
  unsigned short* xb    = (unsigned short*)p; p += BNC * 2;
  unsigned short* wqkvb = (unsigned short*)p; p += 3L * CC * CC * 2;
  float*          bqkv  = (float*)p;          p += 4096;
  unsigned short* Amat  = (unsigned short*)p; p += (long)NN * NN * 2;
  unsigned short* Qb    = (unsigned short*)p; p += BNC * 2;
  unsigned short* Ktb   = (unsigned short*)p; p += BNC * 2;   // tiled Kt
  unsigned short* Vtb   = (unsigned short*)p; p += BNC * 2;   // tiled V5
  unsigned short* QKVt  = (unsigned short*)p; p += BNC * 2;   // [b][c][n]

  // casts + Wp transpose in one launch
  preprocess<<<NCAST + 1024, 256, 0, stream>>>(
      x, Wq, Wk, Wv, bq, bk, bv, Wp, xb, wqkvb, bqkv, Amat);

  // Fused QKV projection: M=1024, N=768, K=256 per batch; 128x128 tiles
  gemm_qkv<<<dim3(BB, 8, 6), 256, 0, stream>>>(xb, wqkvb, bqkv, Qb, Ktb, Vtb);

  // Fused softmax(QK^T)·V -> QKVt[c][n]
  attn_fused<<<dim3(BB, NN / 32), 512, 0, stream>>>(Qb, Ktb, Vtb, QKVt);

  // Z[hw][c] = sum_n Amat[hw][n] * QKVt[c][n] : M=1024, N=256, K=1024, f32 out
  gemm_tile<0, 1><<<dim3(BB, 8, 4), 256, 0, stream>>>(
      Amat, NN, 0L, QKVt, NN, (long)NN * CC, nullptr,
      out, CC, (long)NN * CC, NN);
}